// Round 6
// baseline (304.398 us; speedup 1.0000x reference)
//
#include <hip/hip_runtime.h>

#define BDIM 4
#define LDIM 4096
#define DDIM 1024
#define KTAPS 128
#define LCHUNK 64

typedef __attribute__((ext_vector_type(8))) _Float16 f16x8;
typedef __attribute__((ext_vector_type(4))) float f32x4;

// ---------------------------------------------------------------------------
// fp16 helpers
// ---------------------------------------------------------------------------
__device__ __forceinline__ float f16_to_f(ushort h) {
    return (float)__builtin_bit_cast(_Float16, h);
}
__device__ __forceinline__ ushort f_to_f16(float f) {
    return __builtin_bit_cast(ushort, (_Float16)f);  // v_cvt_f16_f32, RNE
}

__device__ __forceinline__ void load_lds16(const ushort* g, ushort* l) {
    __builtin_amdgcn_global_load_lds(
        (const __attribute__((address_space(1))) void*)g,
        (__attribute__((address_space(3))) void*)l, 16, 0, 0);
}

// ---------------------------------------------------------------------------
// fp32 -> fp16 convert (vectorized, grid-stride)
// ---------------------------------------------------------------------------
__global__ __launch_bounds__(256) void to_f16(const float* __restrict__ in,
                                              ushort* __restrict__ out, int n4) {
    for (int i = blockIdx.x * 256 + threadIdx.x; i < n4; i += gridDim.x * 256) {
        const float4 v = *(const float4*)&in[(size_t)i * 4];
        ushort4 h;
        h.x = f_to_f16(v.x);
        h.y = f_to_f16(v.y);
        h.z = f_to_f16(v.z);
        h.w = f_to_f16(v.w);
        *(ushort4*)&out[(size_t)i * 4] = h;
    }
}

// ---------------------------------------------------------------------------
// 256x256 8-phase f16 NT GEMM: BK=64, 8 waves (2Mx4N), dbuf LDS, K-half
// half-tiles, counted vmcnt(4) once per K-tile, setprio around MFMA.
// ROUND-6 CHANGE: no sched_barrier(0), no explicit lgkmcnt(0) — ds_reads are
// plain loads; the compiler inserts fine-grained lgkmcnt(N) between ds_read
// and MFMA (m97 evidence), so early MFMAs overlap late reads. Explicit
// pinning was the m141 failure mode (510 TF).
// LDS granule layout per K-tile buffer: gran[(kh*4+kg)*256 + row] (16B each)
//   -> ds_read_b128 per 16-lane group = 16 consecutive granules (2-way, free;
//      SQ_LDS_BANK_CONFLICT measured 0 in round 5)
//   -> global_load_lds linear in tid (rule #21: LDS dest linear, layout via
//      per-lane global source address).
// A [M,K] f16 row-major, B [N,K] f16 row-major. OBF=1 -> f16 C, else f32 C.
// ---------------------------------------------------------------------------
template <int OBF>
__global__ __launch_bounds__(512) void gemm256(const ushort* __restrict__ A,
                                               const ushort* __restrict__ B,
                                               void* __restrict__ Cp, int ldc, int K) {
    __shared__ ushort lds[65536];  // 128 KiB: [buf][mat][2048 granules][8]

    const int tid = threadIdx.x;
    const int lane = tid & 63;
    const int w = tid >> 6;
    const int wr = w >> 2;   // M-half (0..1)
    const int wc = w & 3;    // N-quarter (0..3)
    const int r16 = lane & 15;
    const int kgl = lane >> 4;  // k-granule of the MFMA operand (0..3)
    const int NT = K >> 6;      // K-tiles of 64

    // bijective XCD swizzle (nwg % 8 == 0 for our grids)
    const int gx = gridDim.x;
    const int nwg = gx * gridDim.y;
    const int orig = blockIdx.y * gx + blockIdx.x;
    const int q8 = nwg >> 3;
    const int tile = (orig & 7) * q8 + (orig >> 3);
    const int m0 = (tile / gx) * 256;
    const int n0 = (tile % gx) * 256;

    // staging: thread t covers granules t (kg=t>>8) and t+512 (kg+2), row mm=t&255
    const int mm = tid & 255;
    const int kg0 = tid >> 8;
    const ushort* pA0 = A + (size_t)(m0 + mm) * K + kg0 * 8;
    const ushort* pB0 = B + (size_t)(n0 + mm) * K + kg0 * 8;

    f32x4 acc[8][4] = {};

    auto STAGE = [&](const int mat, const int kt, const int kh, const int buf) {
        const ushort* s0 = (mat ? pB0 : pA0) + kt * 64 + kh * 32;
        ushort* l = lds + ((buf * 2 + mat) * 2048 + kh * 1024) * 8;
        load_lds16(s0, l + tid * 8);
        load_lds16(s0 + 16, l + (tid + 512) * 8);
    };

    // phase: 8 ds_read_b128 + optional half-tile stage + barrier + 16 MFMA
    // vm: -1 none, 0 -> vmcnt(0), 4 -> vmcnt(4)  (placed BEFORE final barrier
    // so the barrier makes the per-wave drain collective)
    auto PHASE = [&](const int buf, const int kh, const int ih, const int smat,
                     const int skt, const int skh, const int sbuf, const int vm) {
        const ushort* ab =
            lds + ((buf * 2 + 0) * 2048 + kh * 1024 + kgl * 256 + wr * 128 + ih * 64 + r16) * 8;
        const ushort* bb =
            lds + ((buf * 2 + 1) * 2048 + kh * 1024 + kgl * 256 + wc * 64 + r16) * 8;
        f16x8 a0 = *(const f16x8*)(ab);
        f16x8 a1 = *(const f16x8*)(ab + 128);
        f16x8 a2 = *(const f16x8*)(ab + 256);
        f16x8 a3 = *(const f16x8*)(ab + 384);
        f16x8 b0 = *(const f16x8*)(bb);
        f16x8 b1 = *(const f16x8*)(bb + 128);
        f16x8 b2 = *(const f16x8*)(bb + 256);
        f16x8 b3 = *(const f16x8*)(bb + 384);
        if (skt < NT) STAGE(smat, skt, skh, sbuf);
        __builtin_amdgcn_s_barrier();
        // compiler inserts fine-grained lgkmcnt before each dependent MFMA
        __builtin_amdgcn_s_setprio(1);
        f32x4(*ap)[4] = acc + ih * 4;
        ap[0][0] = __builtin_amdgcn_mfma_f32_16x16x32_f16(a0, b0, ap[0][0], 0, 0, 0);
        ap[0][1] = __builtin_amdgcn_mfma_f32_16x16x32_f16(a0, b1, ap[0][1], 0, 0, 0);
        ap[0][2] = __builtin_amdgcn_mfma_f32_16x16x32_f16(a0, b2, ap[0][2], 0, 0, 0);
        ap[0][3] = __builtin_amdgcn_mfma_f32_16x16x32_f16(a0, b3, ap[0][3], 0, 0, 0);
        ap[1][0] = __builtin_amdgcn_mfma_f32_16x16x32_f16(a1, b0, ap[1][0], 0, 0, 0);
        ap[1][1] = __builtin_amdgcn_mfma_f32_16x16x32_f16(a1, b1, ap[1][1], 0, 0, 0);
        ap[1][2] = __builtin_amdgcn_mfma_f32_16x16x32_f16(a1, b2, ap[1][2], 0, 0, 0);
        ap[1][3] = __builtin_amdgcn_mfma_f32_16x16x32_f16(a1, b3, ap[1][3], 0, 0, 0);
        ap[2][0] = __builtin_amdgcn_mfma_f32_16x16x32_f16(a2, b0, ap[2][0], 0, 0, 0);
        ap[2][1] = __builtin_amdgcn_mfma_f32_16x16x32_f16(a2, b1, ap[2][1], 0, 0, 0);
        ap[2][2] = __builtin_amdgcn_mfma_f32_16x16x32_f16(a2, b2, ap[2][2], 0, 0, 0);
        ap[2][3] = __builtin_amdgcn_mfma_f32_16x16x32_f16(a2, b3, ap[2][3], 0, 0, 0);
        ap[3][0] = __builtin_amdgcn_mfma_f32_16x16x32_f16(a3, b0, ap[3][0], 0, 0, 0);
        ap[3][1] = __builtin_amdgcn_mfma_f32_16x16x32_f16(a3, b1, ap[3][1], 0, 0, 0);
        ap[3][2] = __builtin_amdgcn_mfma_f32_16x16x32_f16(a3, b2, ap[3][2], 0, 0, 0);
        ap[3][3] = __builtin_amdgcn_mfma_f32_16x16x32_f16(a3, b3, ap[3][3], 0, 0, 0);
        __builtin_amdgcn_s_setprio(0);
        if (vm == 0) {
            asm volatile("s_waitcnt vmcnt(0)" ::: "memory");
        } else if (vm > 0) {
            asm volatile("s_waitcnt vmcnt(4)" ::: "memory");
        }
        __builtin_amdgcn_s_barrier();
    };

    // prologue: tile0 (all 4 halves) + tile1 k-half0 -> vmcnt(4) leaves tile1's
    // A/B kh0 in flight, matching steady state.
    STAGE(0, 0, 0, 0);
    STAGE(1, 0, 0, 0);
    STAGE(0, 0, 1, 0);
    STAGE(1, 0, 1, 0);
    if (NT > 1) {
        STAGE(0, 1, 0, 1);
        STAGE(1, 1, 0, 1);
    }
    asm volatile("s_waitcnt vmcnt(4)" ::: "memory");
    __builtin_amdgcn_s_barrier();

    // steady state: group g computes K-tile g from buf g&1.
    // slots: p0 A(g+1,kh1)->nbuf  p1 B(g+1,kh1)->nbuf  p2 A(g+2,kh0)->buf
    //        p3 B(g+2,kh0)->buf, then vmcnt(4) (0 entering the last tile).
    for (int g = 0; g < NT; ++g) {
        const int buf = g & 1;
        const int nbuf = buf ^ 1;
        PHASE(buf, 0, 0, 0, g + 1, 1, nbuf, -1);
        PHASE(buf, 0, 1, 1, g + 1, 1, nbuf, -1);
        PHASE(buf, 1, 0, 0, g + 2, 0, buf, -1);
        PHASE(buf, 1, 1, 1, g + 2, 0, buf,
              (g == NT - 2) ? 0 : ((g == NT - 1) ? -1 : 4));
    }

    // epilogue: C/D layout (m89): col=lane&15 (n-side), row=(lane>>4)*4+q (m-side)
#pragma unroll
    for (int i = 0; i < 8; ++i) {
        const int row = m0 + wr * 128 + i * 16 + kgl * 4;
#pragma unroll
        for (int j = 0; j < 4; ++j) {
            const int col = n0 + wc * 64 + j * 16 + r16;
#pragma unroll
            for (int q = 0; q < 4; ++q) {
                if (OBF) {
                    ((ushort*)Cp)[(size_t)(row + q) * ldc + col] = f_to_f16(acc[i][j][q]);
                } else {
                    ((float*)Cp)[(size_t)(row + q) * ldc + col] = acc[i][j][q];
                }
            }
        }
    }
}

// ---------------------------------------------------------------------------
// conv + gate on fp16 qkv [B,L,3072]; writes gated fp16 [B,L,1024].
// decay geometric => exact IIR for the 128-tap FIR:
//   res[l] = r*res[l-1] + src[l] - decay128*src[l-128],  src = k*v (fp32 state)
// ---------------------------------------------------------------------------
__global__ __launch_bounds__(256) void conv_gate_f16(const ushort* __restrict__ qkvh,
                                                     const float* __restrict__ decay,
                                                     ushort* __restrict__ gh) {
    __shared__ float sdec[KTAPS];
    if (threadIdx.x < KTAPS) sdec[threadIdx.x] = decay[threadIdx.x];
    __syncthreads();

    const int d = blockIdx.y * 256 + threadIdx.x;
    const int b = blockIdx.z;
    const int l0 = blockIdx.x * LCHUNK;

    const float r = sdec[1];
    const float dlast = r * sdec[KTAPS - 1];  // decay[128]
    const size_t rs = 3 * DDIM;

    const ushort* base = qkvh + (size_t)b * LDIM * rs;
    const ushort* qc = base + d;
    const ushort* kc = base + DDIM + d;
    const ushort* vc = base + 2 * DDIM + d;
    ushort* g0 = gh + (size_t)b * LDIM * DDIM + d;

    float res = 0.f;
    int lstart;
    if (l0 == 0) {
        lstart = 0;
    } else {
        const int tmax = (l0 < KTAPS - 1) ? l0 : (KTAPS - 1);
#pragma unroll 4
        for (int t = 0; t <= tmax; ++t) {
            const size_t off = (size_t)(l0 - t) * rs;
            res += sdec[t] * f16_to_f(kc[off]) * f16_to_f(vc[off]);
        }
        g0[(size_t)l0 * DDIM] = f_to_f16(f16_to_f(qc[(size_t)l0 * rs]) * res);
        lstart = l0 + 1;
    }

    for (int l = lstart; l < l0 + LCHUNK; ++l) {
        const size_t off = (size_t)l * rs;
        const float s = f16_to_f(kc[off]) * f16_to_f(vc[off]);
        if (l == 0) {
            res = sdec[0] * s;
        } else {
            float sub = 0.f;
            if (l >= KTAPS) {
                const size_t o2 = (size_t)(l - KTAPS) * rs;
                sub = dlast * f16_to_f(kc[o2]) * f16_to_f(vc[o2]);
            }
            res = r * res + s - sub;
        }
        g0[(size_t)l * DDIM] = f_to_f16(f16_to_f(qc[off]) * res);
    }
}

// ---------------------------------------------------------------------------
// Memory plan (ws proven >= 192MB; uses 168MB):
//   ws[  0.. 96MB) qkvh  f16 [16384,3072]  GEMM1 out
//   ws[ 96..128MB) gh    f16 [16384,1024]  conv out = GEMM2 A
//   ws[128..160MB) xh    f16 [16384,1024]  GEMM1 A
//   ws[160..166MB) wqkvh f16 [3072,1024]   GEMM1 B
//   ws[166..168MB) wouth f16 [1024,1024]   GEMM2 B
// ---------------------------------------------------------------------------
extern "C" void kernel_launch(void* const* d_in, const int* in_sizes, int n_in,
                              void* d_out, int out_size, void* d_ws, size_t ws_size,
                              hipStream_t stream) {
    const float* x = (const float*)d_in[0];
    const float* Wqkv = (const float*)d_in[1];
    const float* Wout = (const float*)d_in[2];
    const float* decay = (const float*)d_in[3];

    const int M = BDIM * LDIM;  // 16384
    const size_t MB = 1024 * 1024;

    ushort* qkvh = (ushort*)d_ws;
    ushort* gh = (ushort*)((char*)d_ws + 96 * MB);
    ushort* xh = (ushort*)((char*)d_ws + 128 * MB);
    ushort* wqkvh = (ushort*)((char*)d_ws + 160 * MB);
    ushort* wouth = (ushort*)((char*)d_ws + 166 * MB);

    // converts
    to_f16<<<2048, 256, 0, stream>>>(x, xh, M * DDIM / 4);
    to_f16<<<1024, 256, 0, stream>>>(Wqkv, wqkvh, 3 * DDIM * DDIM / 4);
    to_f16<<<512, 256, 0, stream>>>(Wout, wouth, DDIM * DDIM / 4);

    // GEMM1: qkvh = xh @ wqkvh^T  [16384,1024]x[3072,1024]^T, f16 out
    dim3 g1(3 * DDIM / 256, M / 256);  // 12 x 64 = 768 wgs (%8==0)
    gemm256<1><<<g1, 512, 0, stream>>>(xh, wqkvh, qkvh, 3 * DDIM, DDIM);

    // conv + gate -> gh
    dim3 g2(LDIM / LCHUNK, DDIM / 256, BDIM);  // 64 x 4 x 4 = 1024 blocks
    conv_gate_f16<<<g2, 256, 0, stream>>>(qkvh, decay, gh);

    // GEMM2: out = gh @ wouth^T  [16384,1024]x[1024,1024]^T, f32 out
    dim3 g3(DDIM / 256, M / 256);  // 4 x 64 = 256 wgs (%8==0)
    gemm256<0><<<g3, 512, 0, stream>>>(gh, wouth, d_out, DDIM, DDIM);
}

// Round 7
// 300.153 us; speedup vs baseline: 1.0141x; 1.0141x over previous
//
#include <hip/hip_runtime.h>

#define BDIM 4
#define LDIM 4096
#define DDIM 1024
#define KTAPS 128
#define LCHUNK 64

typedef __attribute__((ext_vector_type(8))) _Float16 f16x8;
typedef __attribute__((ext_vector_type(4))) float f32x4;

// ---------------------------------------------------------------------------
// fp16 helpers
// ---------------------------------------------------------------------------
__device__ __forceinline__ float f16_to_f(ushort h) {
    return (float)__builtin_bit_cast(_Float16, h);
}
__device__ __forceinline__ ushort f_to_f16(float f) {
    return __builtin_bit_cast(ushort, (_Float16)f);  // v_cvt_f16_f32, RNE
}

__device__ __forceinline__ void load_lds16(const ushort* g, ushort* l) {
    __builtin_amdgcn_global_load_lds(
        (const __attribute__((address_space(1))) void*)g,
        (__attribute__((address_space(3))) void*)l, 16, 0, 0);
}

// counted lgkm wait + scheduling fence (rule 18: MFMA is register-only, the
// "memory" clobber does NOT order it past the asm wait; sched_barrier does)
#define WAITL(N)                                             \
    do {                                                     \
        asm volatile("s_waitcnt lgkmcnt(" #N ")" ::: "memory"); \
        __builtin_amdgcn_sched_barrier(0);                   \
    } while (0)

// ---------------------------------------------------------------------------
// fp32 -> fp16 convert (vectorized, grid-stride)
// ---------------------------------------------------------------------------
__global__ __launch_bounds__(256) void to_f16(const float* __restrict__ in,
                                              ushort* __restrict__ out, int n4) {
    for (int i = blockIdx.x * 256 + threadIdx.x; i < n4; i += gridDim.x * 256) {
        const float4 v = *(const float4*)&in[(size_t)i * 4];
        ushort4 h;
        h.x = f_to_f16(v.x);
        h.y = f_to_f16(v.y);
        h.z = f_to_f16(v.z);
        h.w = f_to_f16(v.w);
        *(ushort4*)&out[(size_t)i * 4] = h;
    }
}

// ---------------------------------------------------------------------------
// 256x256 f16 NT GEMM, round-7 schedule: register read-AHEAD (ds_reads for
// phase p+1 issued during phase p's MFMA window, guarded by COUNTED lgkmcnt),
// B-fragments read once per K-half (24 b128/K-tile/wave, m201 parity),
// 2 barriers per K-tile (end-p1, end-p3), counted vmcnt(4) once per K-tile.
// LDS granule layout per K-tile buffer: gran[(kh*4+kg)*256 + row] (16B each)
//   -> conflict-free ds_read_b128 (measured 0 in rounds 5-6)
//   -> global_load_lds linear in tid (rule #21).
// A [M,K] f16 row-major, B [N,K] f16 row-major. OBF=1 -> f16 C, else f32 C.
// ---------------------------------------------------------------------------
template <int OBF>
__global__ __launch_bounds__(512) void gemm256(const ushort* __restrict__ A,
                                               const ushort* __restrict__ B,
                                               void* __restrict__ Cp, int ldc, int K) {
    __shared__ ushort lds[65536];  // 128 KiB: [buf][mat][2048 granules][8]

    const int tid = threadIdx.x;
    const int lane = tid & 63;
    const int w = tid >> 6;
    const int wr = w >> 2;   // M-half (0..1)
    const int wc = w & 3;    // N-quarter (0..3)
    const int r16 = lane & 15;
    const int kgl = lane >> 4;  // k-granule of the MFMA operand (0..3)
    const int NT = K >> 6;      // K-tiles of 64

    // bijective XCD swizzle (nwg % 8 == 0 for our grids)
    const int gx = gridDim.x;
    const int nwg = gx * gridDim.y;
    const int orig = blockIdx.y * gx + blockIdx.x;
    const int q8 = nwg >> 3;
    const int tile = (orig & 7) * q8 + (orig >> 3);
    const int m0 = (tile / gx) * 256;
    const int n0 = (tile % gx) * 256;

    // staging: thread t covers granules t (kg=t>>8) and t+512 (kg+2), row mm=t&255
    const int mm = tid & 255;
    const int kg0 = tid >> 8;
    const ushort* pA0 = A + (size_t)(m0 + mm) * K + kg0 * 8;
    const ushort* pB0 = B + (size_t)(n0 + mm) * K + kg0 * 8;

    f32x4 acc[8][4] = {};
    f16x8 sA[4], sB[4], bA[4], bB[4];  // ping-pong A sets; per-kh B sets

    auto STAGE = [&](const int mat, const int kt, const int kh, const int buf) {
        const ushort* s0 = (mat ? pB0 : pA0) + kt * 64 + kh * 32;
        ushort* l = lds + ((buf * 2 + mat) * 2048 + kh * 1024) * 8;
        load_lds16(s0, l + tid * 8);
        load_lds16(s0 + 16, l + (tid + 512) * 8);
    };
    auto RD_A = [&](f16x8* dst, const int buf, const int kh, const int ih) {
        const ushort* ab =
            lds + ((buf * 2 + 0) * 2048 + kh * 1024 + kgl * 256 + wr * 128 + ih * 64 + r16) * 8;
        dst[0] = *(const f16x8*)(ab);
        dst[1] = *(const f16x8*)(ab + 128);
        dst[2] = *(const f16x8*)(ab + 256);
        dst[3] = *(const f16x8*)(ab + 384);
    };
    auto RD_B = [&](f16x8* dst, const int buf, const int kh) {
        const ushort* bb =
            lds + ((buf * 2 + 1) * 2048 + kh * 1024 + kgl * 256 + wc * 64 + r16) * 8;
        dst[0] = *(const f16x8*)(bb);
        dst[1] = *(const f16x8*)(bb + 128);
        dst[2] = *(const f16x8*)(bb + 256);
        dst[3] = *(const f16x8*)(bb + 384);
    };
    auto MFMA16 = [&](const f16x8* a, const f16x8* b, const int ih) {
        f32x4(*ap)[4] = acc + ih * 4;
        __builtin_amdgcn_s_setprio(1);
#pragma unroll
        for (int i = 0; i < 4; ++i) {
            ap[i][0] = __builtin_amdgcn_mfma_f32_16x16x32_f16(a[i], b[0], ap[i][0], 0, 0, 0);
            ap[i][1] = __builtin_amdgcn_mfma_f32_16x16x32_f16(a[i], b[1], ap[i][1], 0, 0, 0);
            ap[i][2] = __builtin_amdgcn_mfma_f32_16x16x32_f16(a[i], b[2], ap[i][2], 0, 0, 0);
            ap[i][3] = __builtin_amdgcn_mfma_f32_16x16x32_f16(a[i], b[3], ap[i][3], 0, 0, 0);
        }
        __builtin_amdgcn_s_setprio(0);
    };

    // prologue: tile0 (4 half-tiles) + tile1 kh0 staged; drain tile0 (8 loads)
    STAGE(0, 0, 0, 0);
    STAGE(1, 0, 0, 0);
    STAGE(0, 0, 1, 0);
    STAGE(1, 0, 1, 0);
    if (NT > 1) {
        STAGE(0, 1, 0, 1);
        STAGE(1, 1, 0, 1);
    }
    asm volatile("s_waitcnt vmcnt(4)" ::: "memory");
    __builtin_amdgcn_s_barrier();

    // steady state: tile g from buf=g&1. Stage slots (as rounds 5/6):
    //   p0: A(g+1,kh1)->nbuf  p1: B(g+1,kh1)->nbuf
    //   p2: A(g+2,kh0)->buf   p3: B(g+2,kh0)->buf
    // Reads: p0 issues {sA=A(kh0,ih0), bA=B(kh0)} for ITSELF (tile boundary),
    // then prefetches one phase ahead; counted lgkm guards the consumed set.
    for (int g = 0; g < NT; ++g) {
        const int buf = g & 1;
        const int nbuf = buf ^ 1;
        // ---- p0: MFMA(sA, bA) on kh0/ih0 ----
        RD_A(sA, buf, 0, 0);
        RD_B(bA, buf, 0);
        if (g + 1 < NT) STAGE(0, g + 1, 1, nbuf);
        WAITL(0);                 // sA, bA ready (tile-boundary stall, 1x/tile)
        RD_A(sB, buf, 0, 1);      // prefetch p1's A (drains under MFMA)
        MFMA16(sA, bA, 0);
        // ---- p1: MFMA(sB, bA) on kh0/ih1 ----
        RD_A(sA, buf, 1, 0);      // prefetch p2's A
        RD_B(bB, buf, 1);         // prefetch p2/p3's B
        if (g + 1 < NT) STAGE(1, g + 1, 1, nbuf);
        WAITL(8);                 // sB done (8 newer reads may remain)
        MFMA16(sB, bA, 1);
        __builtin_amdgcn_s_barrier();  // all kh0 reads chip-wide done -> p2/p3 may overwrite kh0
        // ---- p2: MFMA(sA, bB) on kh1/ih0 ----
        RD_A(sB, buf, 1, 1);      // prefetch p3's A
        if (g + 2 < NT) STAGE(0, g + 2, 0, buf);
        WAITL(4);                 // sA, bB done (4 newer remain)
        MFMA16(sA, bB, 0);
        // ---- p3: MFMA(sB, bB) on kh1/ih1 ----
        if (g + 2 < NT) STAGE(1, g + 2, 0, buf);
        WAITL(0);                 // sB done
        MFMA16(sB, bB, 1);
        if (g == NT - 2) {
            asm volatile("s_waitcnt vmcnt(0)" ::: "memory");
        } else if (g < NT - 2) {
            asm volatile("s_waitcnt vmcnt(4)" ::: "memory");  // tile g+1 fully landed
        }
        __builtin_amdgcn_s_barrier();  // tile handoff
    }

    // epilogue: C/D layout (m89): col=lane&15 (n-side), row=(lane>>4)*4+q (m-side)
#pragma unroll
    for (int i = 0; i < 8; ++i) {
        const int row = m0 + wr * 128 + i * 16 + kgl * 4;
#pragma unroll
        for (int j = 0; j < 4; ++j) {
            const int col = n0 + wc * 64 + j * 16 + r16;
#pragma unroll
            for (int q = 0; q < 4; ++q) {
                if (OBF) {
                    ((ushort*)Cp)[(size_t)(row + q) * ldc + col] = f_to_f16(acc[i][j][q]);
                } else {
                    ((float*)Cp)[(size_t)(row + q) * ldc + col] = acc[i][j][q];
                }
            }
        }
    }
}

// ---------------------------------------------------------------------------
// conv + gate on fp16 qkv [B,L,3072]; writes gated fp16 [B,L,1024].
// decay geometric => exact IIR for the 128-tap FIR:
//   res[l] = r*res[l-1] + src[l] - decay128*src[l-128],  src = k*v (fp32 state)
// ---------------------------------------------------------------------------
__global__ __launch_bounds__(256) void conv_gate_f16(const ushort* __restrict__ qkvh,
                                                     const float* __restrict__ decay,
                                                     ushort* __restrict__ gh) {
    __shared__ float sdec[KTAPS];
    if (threadIdx.x < KTAPS) sdec[threadIdx.x] = decay[threadIdx.x];
    __syncthreads();

    const int d = blockIdx.y * 256 + threadIdx.x;
    const int b = blockIdx.z;
    const int l0 = blockIdx.x * LCHUNK;

    const float r = sdec[1];
    const float dlast = r * sdec[KTAPS - 1];  // decay[128]
    const size_t rs = 3 * DDIM;

    const ushort* base = qkvh + (size_t)b * LDIM * rs;
    const ushort* qc = base + d;
    const ushort* kc = base + DDIM + d;
    const ushort* vc = base + 2 * DDIM + d;
    ushort* g0 = gh + (size_t)b * LDIM * DDIM + d;

    float res = 0.f;
    int lstart;
    if (l0 == 0) {
        lstart = 0;
    } else {
        const int tmax = (l0 < KTAPS - 1) ? l0 : (KTAPS - 1);
#pragma unroll 4
        for (int t = 0; t <= tmax; ++t) {
            const size_t off = (size_t)(l0 - t) * rs;
            res += sdec[t] * f16_to_f(kc[off]) * f16_to_f(vc[off]);
        }
        g0[(size_t)l0 * DDIM] = f_to_f16(f16_to_f(qc[(size_t)l0 * rs]) * res);
        lstart = l0 + 1;
    }

    for (int l = lstart; l < l0 + LCHUNK; ++l) {
        const size_t off = (size_t)l * rs;
        const float s = f16_to_f(kc[off]) * f16_to_f(vc[off]);
        if (l == 0) {
            res = sdec[0] * s;
        } else {
            float sub = 0.f;
            if (l >= KTAPS) {
                const size_t o2 = (size_t)(l - KTAPS) * rs;
                sub = dlast * f16_to_f(kc[o2]) * f16_to_f(vc[o2]);
            }
            res = r * res + s - sub;
        }
        g0[(size_t)l * DDIM] = f_to_f16(f16_to_f(qc[off]) * res);
    }
}

// ---------------------------------------------------------------------------
// Memory plan (ws proven >= 192MB; uses 168MB):
//   ws[  0.. 96MB) qkvh  f16 [16384,3072]  GEMM1 out
//   ws[ 96..128MB) gh    f16 [16384,1024]  conv out = GEMM2 A
//   ws[128..160MB) xh    f16 [16384,1024]  GEMM1 A
//   ws[160..166MB) wqkvh f16 [3072,1024]   GEMM1 B
//   ws[166..168MB) wouth f16 [1024,1024]   GEMM2 B
// ---------------------------------------------------------------------------
extern "C" void kernel_launch(void* const* d_in, const int* in_sizes, int n_in,
                              void* d_out, int out_size, void* d_ws, size_t ws_size,
                              hipStream_t stream) {
    const float* x = (const float*)d_in[0];
    const float* Wqkv = (const float*)d_in[1];
    const float* Wout = (const float*)d_in[2];
    const float* decay = (const float*)d_in[3];

    const int M = BDIM * LDIM;  // 16384
    const size_t MB = 1024 * 1024;

    ushort* qkvh = (ushort*)d_ws;
    ushort* gh = (ushort*)((char*)d_ws + 96 * MB);
    ushort* xh = (ushort*)((char*)d_ws + 128 * MB);
    ushort* wqkvh = (ushort*)((char*)d_ws + 160 * MB);
    ushort* wouth = (ushort*)((char*)d_ws + 166 * MB);

    // converts
    to_f16<<<2048, 256, 0, stream>>>(x, xh, M * DDIM / 4);
    to_f16<<<1024, 256, 0, stream>>>(Wqkv, wqkvh, 3 * DDIM * DDIM / 4);
    to_f16<<<512, 256, 0, stream>>>(Wout, wouth, DDIM * DDIM / 4);

    // GEMM1: qkvh = xh @ wqkvh^T  [16384,1024]x[3072,1024]^T, f16 out
    dim3 g1(3 * DDIM / 256, M / 256);  // 12 x 64 = 768 wgs (%8==0)
    gemm256<1><<<g1, 512, 0, stream>>>(xh, wqkvh, qkvh, 3 * DDIM, DDIM);

    // conv + gate -> gh
    dim3 g2(LDIM / LCHUNK, DDIM / 256, BDIM);  // 64 x 4 x 4 = 1024 blocks
    conv_gate_f16<<<g2, 256, 0, stream>>>(qkvh, decay, gh);

    // GEMM2: out = gh @ wouth^T  [16384,1024]x[1024,1024]^T, f32 out
    dim3 g3(DDIM / 256, M / 256);  // 4 x 64 = 256 wgs (%8==0)
    gemm256<0><<<g3, 512, 0, stream>>>(gh, wouth, d_out, DDIM, DDIM);
}

// Round 8
// 283.426 us; speedup vs baseline: 1.0740x; 1.0590x over previous
//
#include <hip/hip_runtime.h>

#define BDIM 4
#define LDIM 4096
#define DDIM 1024
#define KTAPS 128
#define LCHUNK 64

typedef __attribute__((ext_vector_type(8))) _Float16 f16x8;
typedef __attribute__((ext_vector_type(16))) float f32x16;

// ---------------------------------------------------------------------------
// fp16 helpers
// ---------------------------------------------------------------------------
__device__ __forceinline__ float f16_to_f(ushort h) {
    return (float)__builtin_bit_cast(_Float16, h);
}
__device__ __forceinline__ ushort f_to_f16(float f) {
    return __builtin_bit_cast(ushort, (_Float16)f);  // v_cvt_f16_f32, RNE
}

__device__ __forceinline__ void load_lds16(const ushort* g, ushort* l) {
    __builtin_amdgcn_global_load_lds(
        (const __attribute__((address_space(1))) void*)g,
        (__attribute__((address_space(3))) void*)l, 16, 0, 0);
}

// granule swizzle for LDS row r (4 octets of 16B per 64B row); period-16 in r
#define NSWZ(r) ((((r) & 3) ^ (((r) >> 2) & 3)))

// ---------------------------------------------------------------------------
// fused fp32 -> fp16 convert for all three inputs (one launch)
// ---------------------------------------------------------------------------
#define NX4 (BDIM * LDIM * DDIM / 4)        // 4194304
#define NQ4 (3 * DDIM * DDIM / 4)           // 786432
#define NO4 (DDIM * DDIM / 4)               // 262144
__global__ __launch_bounds__(256) void to_f16_all(const float* __restrict__ x,
                                                  const float* __restrict__ wq,
                                                  const float* __restrict__ wo,
                                                  ushort* __restrict__ xh,
                                                  ushort* __restrict__ wqh,
                                                  ushort* __restrict__ woh) {
    const int ntot = NX4 + NQ4 + NO4;
    for (int i = blockIdx.x * 256 + threadIdx.x; i < ntot; i += gridDim.x * 256) {
        const float* src;
        ushort* dst;
        int j = i;
        if (j < NX4) {
            src = x; dst = xh;
        } else if (j < NX4 + NQ4) {
            j -= NX4; src = wq; dst = wqh;
        } else {
            j -= NX4 + NQ4; src = wo; dst = woh;
        }
        const float4 v = *(const float4*)&src[(size_t)j * 4];
        ushort4 h;
        h.x = f_to_f16(v.x);
        h.y = f_to_f16(v.y);
        h.z = f_to_f16(v.z);
        h.w = f_to_f16(v.w);
        *(ushort4*)&dst[(size_t)j * 4] = h;
    }
}

// ---------------------------------------------------------------------------
// fp16 NT GEMM, r4 structure (128x128 tile, BK=32, 4 waves, 3 blocks/CU),
// ROUND-8 CHANGE: 32x32x16 MFMA (8 instrs/K-tile/wave instead of 16, 2x
// FLOP/instr; 2382 TF ubench vs 2075) to relieve the VALU:MFMA issue ratio.
// Wave sub-tile 64x64 = 2x2 of 32x32; acc = 4 x f32x16 (64 AGPR, unchanged).
// A/B fragment map: lane l -> row/col = l&31, k-octet = l>>5 (k = (l>>5)*8+j);
// C/D map (m74/m101 HW-verified): col = lane&31, row = (q&3)+8*(q>>2)+4*(l>>5).
// LDS staging identical to r4 (global_load_lds, pre-swizzled source octets).
// OBF=1 -> f16 C, OBF=0 -> f32 C. XCD-aware tile swizzle.
// ---------------------------------------------------------------------------
template <int OBF>
__global__ __launch_bounds__(256) void gemm_f16(const ushort* __restrict__ A,
                                                const ushort* __restrict__ B,
                                                void* __restrict__ Cp, int ldc, int Kc) {
    __shared__ ushort As[128 * 32];
    __shared__ ushort Bs[128 * 32];

    const int tid = threadIdx.x;

    // bijective XCD swizzle (nwg % 8 == 0 for all our grids)
    const int gx = gridDim.x;
    const int nwg = gx * gridDim.y;
    const int orig = blockIdx.y * gx + blockIdx.x;
    const int q8 = nwg >> 3;
    const int tile = (orig & 7) * q8 + (orig >> 3);
    const int m0 = (tile / gx) * 128;
    const int n0 = (tile % gx) * 128;

    // staging: thread t -> LDS rows t>>2 and t>>2 + 64, octet t&3; inverse-swizzled src
    const int ra = tid >> 2;
    const int ga = tid & 3;
    const int gs = (ga ^ NSWZ(ra)) * 8;

    const ushort* srcA0 = A + (size_t)(m0 + ra) * Kc + gs;
    const ushort* srcA1 = A + (size_t)(m0 + 64 + ra) * Kc + gs;
    const ushort* srcB0 = B + (size_t)(n0 + ra) * Kc + gs;
    const ushort* srcB1 = B + (size_t)(n0 + 64 + ra) * Kc + gs;
    ushort* dstA0 = &As[tid * 8];
    ushort* dstA1 = &As[(tid + 256) * 8];
    ushort* dstB0 = &Bs[tid * 8];
    ushort* dstB1 = &Bs[(tid + 256) * 8];

    const int lane = tid & 63;
    const int w = tid >> 6;
    const int wr = w >> 1, wc = w & 1;  // wave 64x64 sub-tile
    const int l31 = lane & 31;
    const int hi = lane >> 5;           // k-octet half (A/B), +4 row offset (C/D)
    const int nsw = NSWZ(l31 & 15);
    const int arow = wr * 64 + l31;
    const int brow = wc * 64 + l31;

    f32x16 acc[2][2] = {};  // [rb][cb] 32x32 tiles

    for (int kc = 0; kc < Kc; kc += 32) {
        __syncthreads();  // prior iteration's ds_reads complete
        load_lds16(srcA0, dstA0);
        load_lds16(srcA1, dstA1);
        load_lds16(srcB0, dstB0);
        load_lds16(srcB1, dstB1);
        srcA0 += 32; srcA1 += 32; srcB0 += 32; srcB1 += 32;
        __syncthreads();  // vmcnt(0) drained before barrier -> tiles visible

        f16x8 a[2][2], b[2][2];  // [rb/cb][kh]
#pragma unroll
        for (int rb = 0; rb < 2; ++rb)
#pragma unroll
            for (int kh = 0; kh < 2; ++kh)
                a[rb][kh] = *(const f16x8*)&As[(arow + rb * 32) * 32 +
                                               (((2 * kh + hi) ^ nsw) * 8)];
#pragma unroll
        for (int cb = 0; cb < 2; ++cb)
#pragma unroll
            for (int kh = 0; kh < 2; ++kh)
                b[cb][kh] = *(const f16x8*)&Bs[(brow + cb * 32) * 32 +
                                               (((2 * kh + hi) ^ nsw) * 8)];
#pragma unroll
        for (int rb = 0; rb < 2; ++rb)
#pragma unroll
            for (int cb = 0; cb < 2; ++cb) {
                acc[rb][cb] = __builtin_amdgcn_mfma_f32_32x32x16_f16(
                    a[rb][0], b[cb][0], acc[rb][cb], 0, 0, 0);
                acc[rb][cb] = __builtin_amdgcn_mfma_f32_32x32x16_f16(
                    a[rb][1], b[cb][1], acc[rb][cb], 0, 0, 0);
            }
    }

    // epilogue: C/D (m74/m101): col = lane&31, row = (q&3) + 8*(q>>2) + 4*hi
#pragma unroll
    for (int rb = 0; rb < 2; ++rb)
#pragma unroll
        for (int cb = 0; cb < 2; ++cb) {
            const int colb = n0 + wc * 64 + cb * 32 + l31;
            const int rowb = m0 + wr * 64 + rb * 32 + 4 * hi;
#pragma unroll
            for (int q = 0; q < 16; ++q) {
                const int row = rowb + (q & 3) + 8 * (q >> 2);
                if (OBF) {
                    ((ushort*)Cp)[(size_t)row * ldc + colb] = f_to_f16(acc[rb][cb][q]);
                } else {
                    ((float*)Cp)[(size_t)row * ldc + colb] = acc[rb][cb][q];
                }
            }
        }
}

// ---------------------------------------------------------------------------
// conv + gate on fp16 qkv [B,L,3072]; writes gated fp16 [B,L,1024].
// decay geometric => exact IIR for the 128-tap FIR:
//   res[l] = r*res[l-1] + src[l] - decay128*src[l-128],  src = k*v (fp32 state)
// ---------------------------------------------------------------------------
__global__ __launch_bounds__(256) void conv_gate_f16(const ushort* __restrict__ qkvh,
                                                     const float* __restrict__ decay,
                                                     ushort* __restrict__ gh) {
    __shared__ float sdec[KTAPS];
    if (threadIdx.x < KTAPS) sdec[threadIdx.x] = decay[threadIdx.x];
    __syncthreads();

    const int d = blockIdx.y * 256 + threadIdx.x;
    const int b = blockIdx.z;
    const int l0 = blockIdx.x * LCHUNK;

    const float r = sdec[1];
    const float dlast = r * sdec[KTAPS - 1];  // decay[128]
    const size_t rs = 3 * DDIM;

    const ushort* base = qkvh + (size_t)b * LDIM * rs;
    const ushort* qc = base + d;
    const ushort* kc = base + DDIM + d;
    const ushort* vc = base + 2 * DDIM + d;
    ushort* g0 = gh + (size_t)b * LDIM * DDIM + d;

    float res = 0.f;
    int lstart;
    if (l0 == 0) {
        lstart = 0;
    } else {
        const int tmax = (l0 < KTAPS - 1) ? l0 : (KTAPS - 1);
#pragma unroll 4
        for (int t = 0; t <= tmax; ++t) {
            const size_t off = (size_t)(l0 - t) * rs;
            res += sdec[t] * f16_to_f(kc[off]) * f16_to_f(vc[off]);
        }
        g0[(size_t)l0 * DDIM] = f_to_f16(f16_to_f(qc[(size_t)l0 * rs]) * res);
        lstart = l0 + 1;
    }

    for (int l = lstart; l < l0 + LCHUNK; ++l) {
        const size_t off = (size_t)l * rs;
        const float s = f16_to_f(kc[off]) * f16_to_f(vc[off]);
        if (l == 0) {
            res = sdec[0] * s;
        } else {
            float sub = 0.f;
            if (l >= KTAPS) {
                const size_t o2 = (size_t)(l - KTAPS) * rs;
                sub = dlast * f16_to_f(kc[o2]) * f16_to_f(vc[o2]);
            }
            res = r * res + s - sub;
        }
        g0[(size_t)l * DDIM] = f_to_f16(f16_to_f(qc[off]) * res);
    }
}

// ---------------------------------------------------------------------------
// Memory plan (ws proven >= 192MB; uses 168MB):
//   ws[  0.. 96MB) qkvh  f16 [16384,3072]  GEMM1 out
//   ws[ 96..128MB) gh    f16 [16384,1024]  conv out = GEMM2 A
//   ws[128..160MB) xh    f16 [16384,1024]  GEMM1 A
//   ws[160..166MB) wqkvh f16 [3072,1024]   GEMM1 B
//   ws[166..168MB) wouth f16 [1024,1024]   GEMM2 B
// ---------------------------------------------------------------------------
extern "C" void kernel_launch(void* const* d_in, const int* in_sizes, int n_in,
                              void* d_out, int out_size, void* d_ws, size_t ws_size,
                              hipStream_t stream) {
    const float* x = (const float*)d_in[0];
    const float* Wqkv = (const float*)d_in[1];
    const float* Wout = (const float*)d_in[2];
    const float* decay = (const float*)d_in[3];

    const int M = BDIM * LDIM;  // 16384
    const size_t MB = 1024 * 1024;

    ushort* qkvh = (ushort*)d_ws;
    ushort* gh = (ushort*)((char*)d_ws + 96 * MB);
    ushort* xh = (ushort*)((char*)d_ws + 128 * MB);
    ushort* wqkvh = (ushort*)((char*)d_ws + 160 * MB);
    ushort* wouth = (ushort*)((char*)d_ws + 166 * MB);

    // all three converts in one launch
    to_f16_all<<<2048, 256, 0, stream>>>(x, Wqkv, Wout, xh, wqkvh, wouth);

    // GEMM1: qkvh = xh @ wqkvh^T  [16384,1024]x[3072,1024]^T, f16 out
    dim3 g1(3 * DDIM / 128, M / 128);  // 24 x 128 = 3072 wgs (%8==0)
    gemm_f16<1><<<g1, 256, 0, stream>>>(xh, wqkvh, qkvh, 3 * DDIM, DDIM);

    // conv + gate -> gh
    dim3 g2(LDIM / LCHUNK, DDIM / 256, BDIM);  // 64 x 4 x 4 = 1024 blocks
    conv_gate_f16<<<g2, 256, 0, stream>>>(qkvh, decay, gh);

    // GEMM2: out = gh @ wouth^T  [16384,1024]x[1024,1024]^T, f32 out
    dim3 g3(DDIM / 128, M / 128);  // 8 x 128 = 1024 wgs (%8==0)
    gemm_f16<0><<<g3, 256, 0, stream>>>(gh, wouth, d_out, DDIM, DDIM);
}